// Round 1
// 405.675 us; speedup vs baseline: 2.6328x; 2.6328x over previous
//
#include <hip/hip_runtime.h>
#include <math.h>

#define NROWS 131072
#define HID 256
#define NPAR 800
#define MROWS 64
#define NTHREADS 512
#define NBLOCKS (NROWS / MROWS)      // 2048

#define W2F_FRAGS 25600              // 50 col-tiles * 8 k-steps * 64 lanes
#define LDS_HLO 32768
#define LDS_P   65536
#define LDS_TOTAL 116864             // 2*32768 + 32*401*4

typedef __attribute__((ext_vector_type(8))) short s16x8;
typedef __attribute__((ext_vector_type(4))) float f32x4;

__device__ __forceinline__ unsigned short bf16_rne(float f) {
    unsigned u = __float_as_uint(f);
    u += 0x7fffu + ((u >> 16) & 1u);
    return (unsigned short)(u >> 16);
}

// Pre-split W2 (fp32 [256][800]) into bf16 hi/lo fragments laid out in the exact
// per-lane order the MFMA B-operand wants:
//   frag f = (ct*8 + k0)*64 + lane holds 8 bf16 = W2[k0*32 + (lane>>4)*8 + j][ct*16 + (lane&15)]
__global__ void prep_w2(const float* __restrict__ W2, short* __restrict__ wsp)
{
    const int t = blockIdx.x * 256 + threadIdx.x;
    if (t >= W2F_FRAGS) return;
    const int l = t & 63;
    const int g = t >> 6;
    const int ct = g >> 3, k0 = g & 7;
    const int c  = (ct << 4) + (l & 15);
    const int kb = (k0 << 5) + ((l >> 4) << 3);
    s16x8 hi, lo;
#pragma unroll
    for (int j = 0; j < 8; ++j) {
        float v = W2[(size_t)(kb + j) * NPAR + c];
        unsigned short h = bf16_rne(v);
        float hf = __uint_as_float((unsigned)h << 16);
        unsigned short lw = bf16_rne(v - hf);
        hi[j] = (short)h;
        lo[j] = (short)lw;
    }
    ((s16x8*)wsp)[t] = hi;
    ((s16x8*)wsp)[W2F_FRAGS + t] = lo;
}

__global__ __launch_bounds__(NTHREADS, 2)
void rqs_fused(const float* __restrict__ inp,
               const float* __restrict__ W1,
               const float* __restrict__ b1,
               const short* __restrict__ W2F,
               const float* __restrict__ b2,
               float* __restrict__ out)
{
    extern __shared__ char smem[];
    char*  hhi   = smem;                       // [64][256] bf16, XOR-swizzled
    char*  hlo   = smem + LDS_HLO;             // [64][256] bf16, XOR-swizzled
    float* p_lds = (float*)(smem + LDS_P);     // [32][401] fp32 param staging

    const int t    = threadIdx.x;
    const int row0 = blockIdx.x * MROWS;
    const int lane = t & 63;
    const int w    = t >> 6;                   // wave id 0..7

    // ---- identity pass-through: 64 rows x 32 cols = 512 float4, one per thread ----
    {
        const int r = t >> 3, q = t & 7;
        ((float4*)(out + (size_t)(row0 + r) * 64))[q] =
            ((const float4*)(inp + (size_t)(row0 + r) * 64))[q];
    }

    // ---- GEMM1: h = relu(x_id @ W1 + b1), fp32 VALU; split to bf16 hi/lo in LDS ----
    {
        const int j  = t & 255;
        const int rh = __builtin_amdgcn_readfirstlane(t >> 8);   // wave-uniform row half
        float w1v[32];
#pragma unroll
        for (int k = 0; k < 32; ++k) w1v[k] = W1[k * HID + j];
        const float bj = b1[j];
        for (int rr = 0; rr < 32; ++rr) {
            const int r = rh * 32 + rr;
            const float* xr = inp + (size_t)(row0 + r) * 64;     // uniform -> scalar loads
            float s = bj;
#pragma unroll
            for (int k = 0; k < 32; ++k) s = fmaf(xr[k], w1v[k], s);
            s = fmaxf(s, 0.0f);
            unsigned short hs = bf16_rne(s);
            float hf = __uint_as_float((unsigned)hs << 16);
            unsigned short ls = bf16_rne(s - hf);
            int byte = (r << 9) + (j << 1);
            byte ^= (r & 7) << 4;                                // bank swizzle
            *(short*)(hhi + byte) = (short)hs;
            *(short*)(hlo + byte) = (short)ls;
        }
    }
    __syncthreads();

    // ---- GEMM2: params = h @ W2 via 3-split bf16 MFMA (fp32-accurate) ----
    // 50 column-tiles of 16; wave w owns ct = w, w+8, ... (7 tiles for w<2, else 6).
    const s16x8* Bhi = (const s16x8*)W2F;
    const s16x8* Blo = Bhi + W2F_FRAGS;
    const int nct  = (w < 2) ? 7 : 6;
    const int arow = lane & 15;
    const int kgrp = lane >> 4;

    f32x4 acc[7][4];
#pragma unroll
    for (int ci = 0; ci < 7; ++ci)
#pragma unroll
        for (int rt = 0; rt < 4; ++rt)
            acc[ci][rt] = (f32x4){0.f, 0.f, 0.f, 0.f};

#pragma unroll 1
    for (int k0 = 0; k0 < 8; ++k0) {
        s16x8 ahi[4], alo[4];
#pragma unroll
        for (int rt = 0; rt < 4; ++rt) {
            const int row = rt * 16 + arow;
            int byte = (row << 9) + (k0 << 6) + (kgrp << 4);
            byte ^= (row & 7) << 4;
            ahi[rt] = *(const s16x8*)(hhi + byte);
            alo[rt] = *(const s16x8*)(hlo + byte);
        }
#pragma unroll
        for (int ci = 0; ci < 7; ++ci) {
            if (ci < nct) {
                const int ct   = w + (ci << 3);
                const int fidx = ((ct << 3) + k0) * 64 + lane;
                const s16x8 bhi = Bhi[fidx];                     // coalesced 1KB/wave from L2
                const s16x8 blo = Blo[fidx];
#pragma unroll
                for (int rt = 0; rt < 4; ++rt) {
                    acc[ci][rt] = __builtin_amdgcn_mfma_f32_16x16x32_bf16(ahi[rt], bhi, acc[ci][rt], 0, 0, 0);
                    acc[ci][rt] = __builtin_amdgcn_mfma_f32_16x16x32_bf16(ahi[rt], blo, acc[ci][rt], 0, 0, 0);
                    acc[ci][rt] = __builtin_amdgcn_mfma_f32_16x16x32_bf16(alo[rt], bhi, acc[ci][rt], 0, 0, 0);
                }
            }
        }
    }

    // ---- epilogue in 4 phases: (col-half 0/1) x (row-half 0/1); 512 threads = 32 rows x 16 d ----
    float lad_acc[2] = {0.f, 0.f};

#pragma unroll
    for (int chalf = 0; chalf < 2; ++chalf) {
#pragma unroll
        for (int rhalf = 0; rhalf < 2; ++rhalf) {
            __syncthreads();                                    // p_lds safe to overwrite
            const int c0 = chalf * 25;
#pragma unroll
            for (int ci = 0; ci < 7; ++ci) {
                const int ct = w + (ci << 3);
                if (ci < nct && ct >= c0 && ct < c0 + 25) {
                    const float bias = b2[(ct << 4) + arow];
                    const int col = ((ct - c0) << 4) + arow;    // 0..399
#pragma unroll
                    for (int rr = 0; rr < 2; ++rr) {
                        const int rt = rhalf * 2 + rr;
                        const f32x4 v = acc[ci][rt];
                        const int rowl = (rr << 4) + (kgrp << 2);   // 0..31 (+reg)
                        p_lds[(rowl + 0) * 401 + col] = v[0] + bias;
                        p_lds[(rowl + 1) * 401 + col] = v[1] + bias;
                        p_lds[(rowl + 2) * 401 + col] = v[2] + bias;
                        p_lds[(rowl + 3) * 401 + col] = v[3] + bias;
                    }
                }
            }
            __syncthreads();

            // one (row, d) per thread
            {
                const int r_l = t >> 4;
                const int dl  = t & 15;
                const float* p = &p_lds[r_l * 401 + dl * 25];
                float pv[25];
#pragma unroll
                for (int j = 0; j < 25; ++j) pv[j] = p[j];

                float cw[9], ch[9], dd[9];
                {
                    float mw = pv[0];
#pragma unroll
                    for (int j = 1; j < 8; ++j) mw = fmaxf(mw, pv[j]);
                    float e[8], sw = 0.f;
#pragma unroll
                    for (int j = 0; j < 8; ++j) { e[j] = __expf(pv[j] - mw); sw += e[j]; }
                    const float scale = 0.992f / sw;
                    float run = 0.f;
                    cw[0] = 0.f;
#pragma unroll
                    for (int j = 0; j < 8; ++j) { run += 0.001f + e[j] * scale; cw[j + 1] = run; }
                    const float icn = 1.0f / fmaxf(cw[8], 1e-12f);
#pragma unroll
                    for (int j = 1; j <= 8; ++j) cw[j] *= icn;
                }
                {
                    float mh = pv[8];
#pragma unroll
                    for (int j = 1; j < 8; ++j) mh = fmaxf(mh, pv[8 + j]);
                    float e[8], sh = 0.f;
#pragma unroll
                    for (int j = 0; j < 8; ++j) { e[j] = __expf(pv[8 + j] - mh); sh += e[j]; }
                    const float scale = 0.992f / sh;
                    float run = 0.f;
                    ch[0] = 0.f;
#pragma unroll
                    for (int j = 0; j < 8; ++j) { run += 0.001f + e[j] * scale; ch[j + 1] = run; }
                    const float icn = 1.0f / fmaxf(ch[8], 1e-12f);
#pragma unroll
                    for (int j = 1; j <= 8; ++j) ch[j] *= icn;
                }
#pragma unroll
                for (int j = 0; j < 9; ++j) {
                    const float u = pv[16 + j];
                    dd[j] = 0.001f + fmaxf(u, 0.f) + log1pf(__expf(-fabsf(u)));
                }

                const int grow = row0 + rhalf * 32 + r_l;
                const int d = chalf * 16 + dl;
                const float x = inp[(size_t)grow * 64 + 32 + d];
                const float xs = fminf(fmaxf((x + 10.0f) * 0.05f, 0.f), 1.f);
                int b = 0;
#pragma unroll
                for (int j = 1; j <= 8; ++j) b += (xs >= cw[j]) ? 1 : 0;
                b = min(b, 7);

                float xk = 0.f, wk = 0.f, yk = 0.f, hk = 0.f, dk = 0.f, dk1 = 0.f;
#pragma unroll
                for (int j = 0; j < 8; ++j) {
                    if (b == j) {
                        xk = cw[j]; wk = cw[j + 1] - cw[j];
                        yk = ch[j]; hk = ch[j + 1] - ch[j];
                        dk = dd[j]; dk1 = dd[j + 1];
                    }
                }

                const float EPSf = 1e-12f;
                const float tt = fminf(fmaxf((xs - xk) / (wk + EPSf), 0.f), 1.f);
                const float a = (hk + EPSf) / (wk + EPSf);
                const float omt = 1.f - tt;
                const float tomt = tt * omt;
                const float num = a * tt * tt + dk * tomt;
                const float den = a + (dk + dk1 - 2.f * a) * tomt;
                const float sres = num / (den + EPSf);
                const float ys = yk + hk * sres;
                float y = ys * 20.0f - 10.0f;
                const float dnum = a * a * (dk1 * tt * tt + 2.f * a * tomt + dk * omt * omt);
                const float dydx = dnum / (den * den + EPSf);
                float lad = __logf(fmaxf(dydx, 1e-12f));

                const bool inside = (x >= -10.0f) && (x <= 10.0f);
                if (!inside) { y = x; lad = 0.0f; }

                out[(size_t)grow * 64 + 32 + d] = y;
                lad_acc[rhalf] += lad;
            }
        }
    }

    // ---- logabsdet: reduce 16 d-lanes per row (within-wave groups of 16) ----
    float s0 = lad_acc[0], s1 = lad_acc[1];
    s0 += __shfl_xor(s0, 1, 64); s0 += __shfl_xor(s0, 2, 64);
    s0 += __shfl_xor(s0, 4, 64); s0 += __shfl_xor(s0, 8, 64);
    s1 += __shfl_xor(s1, 1, 64); s1 += __shfl_xor(s1, 2, 64);
    s1 += __shfl_xor(s1, 4, 64); s1 += __shfl_xor(s1, 8, 64);
    if ((t & 15) == 0) {
        const int r_l = t >> 4;
        out[(size_t)NROWS * 64 + row0 + r_l]      = s0;
        out[(size_t)NROWS * 64 + row0 + 32 + r_l] = s1;
    }
}

extern "C" void kernel_launch(void* const* d_in, const int* in_sizes, int n_in,
                              void* d_out, int out_size, void* d_ws, size_t ws_size,
                              hipStream_t stream) {
    const float* inp = (const float*)d_in[0];
    const float* W1  = (const float*)d_in[1];
    const float* b1  = (const float*)d_in[2];
    const float* W2  = (const float*)d_in[3];
    const float* b2  = (const float*)d_in[4];
    float* out = (float*)d_out;
    short* wsp = (short*)d_ws;      // needs 819200 B for W2 hi/lo fragments

    static bool attr_done = false;
    if (!attr_done) {
        hipFuncSetAttribute((const void*)rqs_fused,
                            hipFuncAttributeMaxDynamicSharedMemorySize, LDS_TOTAL);
        attr_done = true;
    }

    hipLaunchKernelGGL(prep_w2, dim3(100), dim3(256), 0, stream, W2, wsp);
    hipLaunchKernelGGL(rqs_fused, dim3(NBLOCKS), dim3(NTHREADS), LDS_TOTAL, stream,
                       inp, W1, b1, (const short*)wsp, b2, out);
}